// Round 5
// baseline (403.986 us; speedup 1.0000x reference)
//
#include <hip/hip_runtime.h>

// Frequency-domain room sim, 3-kernel phase split.
//   SF = DFT(sound_field) per cell (unnormalized); per block b:
//     T = clip(res,0,1) * (SF + DFT(env_b));  mic_b = IDFT(T[mic])/1024;
//     SF = box3x3x3(T)   (pointwise per bin -> recursion independent per bin)
// P1: all env FFTs (2 real cells per complex FFT, BOTH FFTs of a 4-cell WG
//     interleaved per pass -> 6 barriers total), direct uint4 stores of the
//     (b,bin,cell) fp16 transposed spectra. XCD-chunked blockIdx swizzle so
//     WGs sharing a 64B output line merge their sectors in one XCD's L2.
//     Bin 512 (Nyquist, exactly real) is prepacked into Et[k=0].imag.
// P2: 512 WGs (one per bin 1..511; WG0 runs bins {0,512} packed as a real
//     pair); 16-block recursion in registers; separable box via S/S2 double
//     LDS buffer -> 2 barriers per block-iter.
// P3: 16 inverse FFTs of the mic spectra.

#define NFFT   1024
#define NF     513
#define NKP    257
#define NCELLS 4096
#define MICQ   136      // x*16+y = 8*16+8
#define PI2    6.28318530717958647692f

// FFT LDS skew: conflict-checked <=3-way for all pass strides + bitrev gather
__device__ __forceinline__ int IDX(int i) { return i + (i >> 5) + ((i >> 6) << 3); }

__device__ __forceinline__ float clip01(float v) { return fminf(fmaxf(v, 0.0f), 1.0f); }
__device__ __forceinline__ unsigned pkh2(float a, float b) {
    union { _Float16 h[2]; unsigned u; } z;
    z.h[0] = (_Float16)a; z.h[1] = (_Float16)b;
    return z.u;
}
__device__ __forceinline__ float h2lo(unsigned u) {
    union { unsigned u; _Float16 h[2]; } z; z.u = u; return (float)z.h[0];
}
__device__ __forceinline__ float h2hi(unsigned u) {
    union { unsigned u; _Float16 h[2]; } z; z.u = u; return (float)z.h[1];
}
__device__ __forceinline__ unsigned cmp4(const uint4& v, int c) {
    return c == 0 ? v.x : c == 1 ? v.y : c == 2 ? v.z : v.w;
}
__device__ __forceinline__ float f4c(const float4& v, int c) {
    return c == 0 ? v.x : c == 1 ? v.y : c == 2 ? v.z : v.w;
}

// ---------------- P1 ----------------
// WG = (block b, 4 cells); two packed complex FFTs interleaved. Grid 16*1024.
__global__ __launch_bounds__(256) void k_p1(
    const float* __restrict__ tf, const float* __restrict__ imp,
    const float* __restrict__ noise, unsigned* __restrict__ Et,
    unsigned* __restrict__ TFt)
{
    __shared__ float re0[1184], im0[1184], re1[1184], im1[1184];

    const int tid = threadIdx.x;
    // XCD-chunked swizzle: consecutive work on one XCD -> L2 write merging
    const int bid = blockIdx.x;
    const int w   = ((bid & 7) << 11) | (bid >> 3);
    const int b   = w >> 10;
    const int c0  = (w & 1023) << 2;

    // per-thread twiddles for the 5 fused (2x radix-2) DIF passes
    float2 tu0[5], tu1[5], tl[5];
    #pragma unroll
    for (int p = 0; p < 5; ++p) {
        const int lgU = 9 - 2 * p, lgL = lgU - 1, LL = 1 << lgL;
        const int j = tid & (LL - 1);
        const int iu0 = j << (9 - lgU), iu1 = (j + LL) << (9 - lgU), il = j << (9 - lgL);
        float s, c;
        __sincosf(-PI2 * (1.0f / 1024.0f) * (float)iu0, &s, &c); tu0[p] = make_float2(c, s);
        __sincosf(-PI2 * (1.0f / 1024.0f) * (float)iu1, &s, &c); tu1[p] = make_float2(c, s);
        __sincosf(-PI2 * (1.0f / 1024.0f) * (float)il,  &s, &c); tl[p]  = make_float2(c, s);
    }

    // interp coefficients for this thread's 4 samples (n = 4*tid + c)
    int lo_[4], hi_[4]; float w_[4];
    #pragma unroll
    for (int c = 0; c < 4; ++c) {
        int n = 4 * tid + c;
        float coord = (n + 0.5f) * (16.0f / 1024.0f) - 0.5f;
        coord = fminf(fmaxf(coord, 0.0f), 15.0f);
        int lo = (int)coord;
        lo_[c] = lo;
        hi_[c] = lo + 1 > 15 ? 15 : lo + 1;
        w_[c]  = coord - (float)lo;
    }

    // env for 4 cells; FFT0 = cells c0,c0+1 ; FFT1 = cells c0+2,c0+3
    {
        const float* ipr = imp + ((size_t)b * NCELLS + c0) * 16;
        const float4 nz0 = *(const float4*)(noise + ((size_t)b * NCELLS + c0 + 0) * NFFT + 4 * tid);
        const float4 nz1 = *(const float4*)(noise + ((size_t)b * NCELLS + c0 + 1) * NFFT + 4 * tid);
        const float4 nz2 = *(const float4*)(noise + ((size_t)b * NCELLS + c0 + 2) * NFFT + 4 * tid);
        const float4 nz3 = *(const float4*)(noise + ((size_t)b * NCELLS + c0 + 3) * NFFT + 4 * tid);
        #pragma unroll
        for (int c = 0; c < 4; ++c) {
            int n = 4 * tid + c;
            float wl = w_[c], wh = 1.0f - w_[c];
            float e0 = clip01(ipr[lo_[c]]      * wh + ipr[hi_[c]]      * wl) * f4c(nz0, c);
            float e1 = clip01(ipr[16 + lo_[c]] * wh + ipr[16 + hi_[c]] * wl) * f4c(nz1, c);
            float e2 = clip01(ipr[32 + lo_[c]] * wh + ipr[32 + hi_[c]] * wl) * f4c(nz2, c);
            float e3 = clip01(ipr[48 + lo_[c]] * wh + ipr[48 + hi_[c]] * wl) * f4c(nz3, c);
            int ix = IDX(n);
            re0[ix] = e0; im0[ix] = e1;
            re1[ix] = e2; im1[ix] = e3;
        }
    }
    __syncthreads();

    // forward FFT: 10 radix-2 DIF stages, fused 2/pass, BOTH FFTs per barrier
    #pragma unroll
    for (int p = 0; p < 5; ++p) {
        const int lgU = 9 - 2 * p, lgL = lgU - 1, LL = 1 << lgL;
        const int j = tid & (LL - 1), g = tid >> lgL;
        const int base = (g << (lgL + 2)) + j;
        const int q0 = IDX(base), q1 = IDX(base + LL);
        const int q2 = IDX(base + 2 * LL), q3 = IDX(base + 3 * LL);
        const float2 w0 = tu0[p], w1 = tu1[p], wl = tl[p];
        {   // FFT0
            float a0r = re0[q0], a0i = im0[q0], a1r = re0[q1], a1i = im0[q1];
            float a2r = re0[q2], a2i = im0[q2], a3r = re0[q3], a3i = im0[q3];
            float u0r = a0r + a2r, u0i = a0i + a2i;
            float d0r = a0r - a2r, d0i = a0i - a2i;
            float u2r = d0r * w0.x - d0i * w0.y, u2i = d0r * w0.y + d0i * w0.x;
            float u1r = a1r + a3r, u1i = a1i + a3i;
            float d1r = a1r - a3r, d1i = a1i - a3i;
            float u3r = d1r * w1.x - d1i * w1.y, u3i = d1r * w1.y + d1i * w1.x;
            float e0r = u0r - u1r, e0i = u0i - u1i;
            float e1r = u2r - u3r, e1i = u2i - u3i;
            re0[q0] = u0r + u1r;               im0[q0] = u0i + u1i;
            re0[q1] = e0r * wl.x - e0i * wl.y; im0[q1] = e0r * wl.y + e0i * wl.x;
            re0[q2] = u2r + u3r;               im0[q2] = u2i + u3i;
            re0[q3] = e1r * wl.x - e1i * wl.y; im0[q3] = e1r * wl.y + e1i * wl.x;
        }
        {   // FFT1
            float a0r = re1[q0], a0i = im1[q0], a1r = re1[q1], a1i = im1[q1];
            float a2r = re1[q2], a2i = im1[q2], a3r = re1[q3], a3i = im1[q3];
            float u0r = a0r + a2r, u0i = a0i + a2i;
            float d0r = a0r - a2r, d0i = a0i - a2i;
            float u2r = d0r * w0.x - d0i * w0.y, u2i = d0r * w0.y + d0i * w0.x;
            float u1r = a1r + a3r, u1i = a1i + a3i;
            float d1r = a1r - a3r, d1i = a1i - a3i;
            float u3r = d1r * w1.x - d1i * w1.y, u3i = d1r * w1.y + d1i * w1.x;
            float e0r = u0r - u1r, e0i = u0i - u1i;
            float e1r = u2r - u3r, e1i = u2i - u3i;
            re1[q0] = u0r + u1r;               im1[q0] = u0i + u1i;
            re1[q1] = e0r * wl.x - e0i * wl.y; im1[q1] = e0r * wl.y + e0i * wl.x;
            re1[q2] = u2r + u3r;               im1[q2] = u2i + u3i;
            re1[q3] = e1r * wl.x - e1i * wl.y; im1[q3] = e1r * wl.y + e1i * wl.x;
        }
        __syncthreads();
    }

    // split packed spectra -> direct uint4 stores (4 cells per bin line).
    // Lane 0 defers kq=0's store and prepacks E512.re into its imag halves.
    float e0sv0 = 0.f, e0sv1 = 0.f, e0sv2 = 0.f, e0sv3 = 0.f;
    #pragma unroll
    for (int it = 0; it < 3; ++it) {
        int kq = tid + it * 256;
        if (kq < NF) {
            int s  = IDX(__brev(kq) >> 22);
            int s2 = IDX(__brev((1024 - kq) & 1023) >> 22);
            float f0r = re0[s],  f0i = im0[s];
            float g0r = re0[s2], g0i = im0[s2];
            float f1r = re1[s],  f1i = im1[s];
            float g1r = re1[s2], g1i = im1[s2];
            float a0r = 0.5f * (f0r + g0r), a0i = 0.5f * (f0i - g0i);
            float b0r = 0.5f * (f0i + g0i), b0i = 0.5f * (g0r - f0r);
            float a1r = 0.5f * (f1r + g1r), a1i = 0.5f * (f1i - g1i);
            float b1r = 0.5f * (f1i + g1i), b1i = 0.5f * (g1r - f1r);
            uint4 u = { pkh2(a0r, a0i), pkh2(b0r, b0i), pkh2(a1r, a1i), pkh2(b1r, b1i) };
            if (kq == 0) {
                e0sv0 = a0r; e0sv1 = b0r; e0sv2 = a1r; e0sv3 = b1r;   // defer
            } else {
                *(uint4*)(Et + ((size_t)b * NF + kq) * NCELLS + c0) = u;
            }
            if (kq == 512) {
                uint4 u0 = { pkh2(e0sv0, a0r), pkh2(e0sv1, b0r),
                             pkh2(e0sv2, a1r), pkh2(e0sv3, b1r) };
                *(uint4*)(Et + ((size_t)b * NF + 0) * NCELLS + c0) = u0;
            }
        }
    }

    // tf: clip + pack bin pairs, direct uint4 store per kp
    {
        const float* r0 = tf + ((size_t)b * NCELLS + c0 + 0) * NF;
        const float* r1 = r0 + NF;
        const float* r2 = r1 + NF;
        const float* r3 = r2 + NF;
        for (int kp = tid; kp < NKP; kp += 256) {
            bool hv = kp < 256;
            uint4 u;
            u.x = pkh2(clip01(r0[2 * kp]), hv ? clip01(r0[2 * kp + 1]) : 0.0f);
            u.y = pkh2(clip01(r1[2 * kp]), hv ? clip01(r1[2 * kp + 1]) : 0.0f);
            u.z = pkh2(clip01(r2[2 * kp]), hv ? clip01(r2[2 * kp + 1]) : 0.0f);
            u.w = pkh2(clip01(r3[2 * kp]), hv ? clip01(r3[2 * kp + 1]) : 0.0f);
            *(uint4*)(TFt + ((size_t)b * NKP + kp) * NCELLS + c0) = u;
        }
    }
}

// ---------------- P2 ----------------
// Grid 512. WG k = bin k; WG 0 runs bins {0,512} packed (both exactly real,
// bin0 in .x, bin512 in .y; E prepacked by P1, tf512 via extra stream).
__global__ __launch_bounds__(256) void k_p2(
    const unsigned* __restrict__ Et, const unsigned* __restrict__ TFt,
    float2* __restrict__ ms)
{
    __shared__ float2 S [256 * 17];
    __shared__ float2 S2[256 * 17];

    const int q = threadIdx.x;
    const int k = blockIdx.x;
    const int kp = k >> 1, sel = k & 1;
    const int x = q >> 4, y = q & 15;
    const bool isk0 = (k == 0);

    float2 SF[16];
    #pragma unroll
    for (int z = 0; z < 16; ++z) SF[z] = make_float2(0.f, 0.f);

    uint4 EB[2][4], TB[2][4], T2[2][4];
    {
        const uint4* ep = (const uint4*)(Et + (size_t)k * NCELLS + (q << 4));
        const uint4* tp = (const uint4*)(TFt + (size_t)kp * NCELLS + (q << 4));
        EB[0][0] = ep[0]; EB[0][1] = ep[1]; EB[0][2] = ep[2]; EB[0][3] = ep[3];
        TB[0][0] = tp[0]; TB[0][1] = tp[1]; TB[0][2] = tp[2]; TB[0][3] = tp[3];
        if (isk0) {
            const uint4* t2 = (const uint4*)(TFt + (size_t)256 * NCELLS + (q << 4));
            T2[0][0] = t2[0]; T2[0][1] = t2[1]; T2[0][2] = t2[2]; T2[0][3] = t2[3];
        }
    }

    #pragma unroll
    for (int b = 0; b < 16; ++b) {
        const int cur = b & 1, nxt = cur ^ 1;
        if (b + 1 < 16) {
            const uint4* ep = (const uint4*)(Et + ((size_t)(b + 1) * NF + k) * NCELLS + (q << 4));
            const uint4* tp = (const uint4*)(TFt + ((size_t)(b + 1) * NKP + kp) * NCELLS + (q << 4));
            EB[nxt][0] = ep[0]; EB[nxt][1] = ep[1]; EB[nxt][2] = ep[2]; EB[nxt][3] = ep[3];
            TB[nxt][0] = tp[0]; TB[nxt][1] = tp[1]; TB[nxt][2] = tp[2]; TB[nxt][3] = tp[3];
            if (isk0) {
                const uint4* t2 = (const uint4*)(TFt + ((size_t)(b + 1) * NKP + 256) * NCELLS + (q << 4));
                T2[nxt][0] = t2[0]; T2[nxt][1] = t2[1]; T2[nxt][2] = t2[2]; T2[nxt][3] = t2[3];
            }
        }

        // T = r * (SF + E)   (componentwise; WG0: r = (tf0, tf512))
        float2 T[16];
        #pragma unroll
        for (int z = 0; z < 16; ++z) {
            unsigned eu = cmp4(EB[cur][z >> 2], z & 3);
            unsigned tu = cmp4(TB[cur][z >> 2], z & 3);
            float rx, ry;
            if (isk0) { rx = h2lo(tu); ry = h2lo(cmp4(T2[cur][z >> 2], z & 3)); }
            else      { float r = sel ? h2hi(tu) : h2lo(tu); rx = r; ry = r; }
            T[z] = make_float2(rx * (SF[z].x + h2lo(eu)),
                               ry * (SF[z].y + h2hi(eu)));
        }
        if (q == MICQ) {
            if (isk0) {
                ms[b * NF + 0]   = make_float2(T[8].x, 0.0f);
                ms[b * NF + 512] = make_float2(T[8].y, 0.0f);
            } else {
                ms[b * NF + k] = T[8];
            }
        }

        // z-sum in registers
        float2 Z[16];
        #pragma unroll
        for (int z = 0; z < 16; ++z) {
            float zr = T[z].x, zi = T[z].y;
            if (z > 0)  { zr += T[z - 1].x; zi += T[z - 1].y; }
            if (z < 15) { zr += T[z + 1].x; zi += T[z + 1].y; }
            Z[z] = make_float2(zr, zi);
        }
        #pragma unroll
        for (int z = 0; z < 16; ++z) S[q * 17 + z] = Z[z];
        __syncthreads();
        float2 Y[16];
        #pragma unroll
        for (int z = 0; z < 16; ++z) {
            float yr = Z[z].x, yi = Z[z].y;
            if (y > 0)  { float2 v = S[(q - 1) * 17 + z]; yr += v.x; yi += v.y; }
            if (y < 15) { float2 v = S[(q + 1) * 17 + z]; yr += v.x; yi += v.y; }
            Y[z] = make_float2(yr, yi);
            S2[q * 17 + z] = Y[z];
        }
        __syncthreads();
        #pragma unroll
        for (int z = 0; z < 16; ++z) {
            float sr = Y[z].x, si = Y[z].y;
            if (x > 0)  { float2 v = S2[(q - 16) * 17 + z]; sr += v.x; si += v.y; }
            if (x < 15) { float2 v = S2[(q + 16) * 17 + z]; sr += v.x; si += v.y; }
            SF[z] = make_float2(sr, si);
        }
        // no barrier here: next iter's S-write is fenced by the next bar1
    }
}

// ---------------- P3 ----------------
__device__ __forceinline__ int pd(int i) { return i + (i >> 5); }

__global__ __launch_bounds__(256) void k_p3(
    const float2* __restrict__ ms, float* __restrict__ out)
{
    __shared__ float2 FD[1056];
    const int b = blockIdx.x, tid = threadIdx.x;

    for (int j = tid; j < NFFT; j += 256) {
        int jj = (j <= 512) ? j : 1024 - j;
        float2 v = ms[b * NF + jj];
        if (j > 512) v.y = -v.y;
        FD[pd(__brev(j) >> 22)] = v;
    }
    __syncthreads();

    for (int lg = 0; lg <= 9; ++lg) {
        const int len = 1 << lg;
        for (int pr = tid; pr < 512; pr += 256) {
            const int jj = pr & (len - 1);
            const int i0 = ((pr >> lg) << (lg + 1)) + jj;
            const int i1 = i0 + len;
            const int iw = jj << (9 - lg);
            float sn, cs;
            __sincosf(-PI2 * (1.0f / 1024.0f) * (float)iw, &sn, &cs);
            float2 a = FD[pd(i0)], bb = FD[pd(i1)];
            float tr = bb.x * cs + bb.y * sn;
            float ti = bb.y * cs - bb.x * sn;
            FD[pd(i0)] = make_float2(a.x + tr, a.y + ti);
            FD[pd(i1)] = make_float2(a.x - tr, a.y - ti);
        }
        __syncthreads();
    }
    for (int t = tid; t < NFFT; t += 256)
        out[b * NFFT + t] = FD[pd(t)].x * (1.0f / 1024.0f);
}

extern "C" void kernel_launch(void* const* d_in, const int* in_sizes, int n_in,
                              void* d_out, int out_size, void* d_ws, size_t ws_size,
                              hipStream_t stream)
{
    const float* tf    = (const float*)d_in[1];
    const float* imp   = (const float*)d_in[2];
    const float* noise = (const float*)d_in[3];
    float* out = (float*)d_out;

    unsigned* Et  = (unsigned*)d_ws;                             // 16*513*4096 u32
    unsigned* TFt = Et + (size_t)16 * NF * NCELLS;               // 16*257*4096 u32
    float2*   ms  = (float2*)(TFt + (size_t)16 * NKP * NCELLS);  // 16*513 c64

    k_p1<<<16 * 1024, 256, 0, stream>>>(tf, imp, noise, Et, TFt);
    k_p2<<<512, 256, 0, stream>>>(Et, TFt, ms);
    k_p3<<<16, 256, 0, stream>>>(ms, out);
}